// Round 8
// baseline (1457.107 us; speedup 1.0000x reference)
//
#include <hip/hip_runtime.h>
#include <hip/hip_bf16.h>
#include <hip/hip_cooperative_groups.h>

namespace cg = cooperative_groups;

#define LNUM 4
#define BB 16
#define SS 16
#define KVC 2048
#define HH 6
#define DD 128
#define HIDN 768
#define FFN 2048
#define NCH 17
#define ATT_SCALE 0.08838834764831845f
#define VT_PAD 136
#define OSH_PAD 132
#define AP 776           // u16 stride for [16][768] LDS tiles
#define AP3 1032         // u16 stride for [16][1024] LDS tiles

typedef unsigned short u16;
typedef short s16x8 __attribute__((ext_vector_type(8)));
typedef unsigned short u16x4 __attribute__((ext_vector_type(4)));
typedef float f32x4 __attribute__((ext_vector_type(4)));

__device__ __forceinline__ short f2bfs(float f) {
    __hip_bfloat16 h = __float2bfloat16(f);
    return *reinterpret_cast<short*>(&h);
}

struct MegaArgs {
    const float *emb, *kc, *vc;
    const float *Wq, *Wk, *Wv, *Wo, *Wg, *Wu, *Wd;
    const float *bq, *bk, *bv, *ln1, *ln2, *normf;
    u16 *WqT, *WkT, *WvT, *WoT, *WgT, *WuT, *WdT;
    float *h;
    u16 *qr, *kr, *vr, *oa, *fb;
    float *po, *pml;
    float2 *tab;
    float *out;
};

__global__ __launch_bounds__(256, 3) void mega_k(MegaArgs a) {
    cg::grid_group gg = cg::this_grid();
    __shared__ __align__(16) char SM[39424];
    const int tid = threadIdx.x, wid = tid >> 6, lane = tid & 63;
    const int r = lane & 15, qg = lane >> 4;
    const size_t WQKV = (size_t)HIDN * HH * DD;
    const size_t WMLP = (size_t)HIDN * FFN;
    const size_t KVOFF = (size_t)BB * HH * KVC * DD;

    // ================= phase 0: weight transpose + h copy + rope table ================
    {
        u16 (*T)[65] = (u16(*)[65])SM;
        for (int t = blockIdx.x; t < 6912 + 192 + 1; t += gridDim.x) {
            if (t < 6912) {
                int z = t / 1728, idx = t % 1728;
                const float* in; u16* out; int K, N, nx, tt;
                if (idx < 432)      { tt = idx % 144; K = 768;  N = 768;  nx = 12;
                                      int w = idx / 144;
                                      in = (w==0)?a.Wq:(w==1)?a.Wk:a.Wv;
                                      out = (w==0)?a.WqT:(w==1)?a.WkT:a.WvT; }
                else if (idx < 576) { tt = idx - 432; K = 768;  N = 768;  nx = 12;
                                      in = a.Wo; out = a.WoT; }
                else if (idx < 1344){ tt = (idx - 576) % 384; K = 768; N = 2048; nx = 32;
                                      in = (idx < 960) ? a.Wg : a.Wu;
                                      out = (idx < 960) ? a.WgT : a.WuT; }
                else                { tt = idx - 1344; K = 2048; N = 768; nx = 12;
                                      in = a.Wd; out = a.WdT; }
                int n0 = (tt % nx) * 64, k0 = (tt / nx) * 64;
                in  += (size_t)z * K * N;
                out += (size_t)z * K * N;
#pragma unroll
                for (int i = 0; i < 16; ++i) {
                    int f = i * 256 + tid;
                    int k = f >> 6, n = f & 63;
                    T[k][n] = (u16)f2bfs(in[(size_t)(k0 + k) * N + n0 + n]);
                }
                __syncthreads();
#pragma unroll
                for (int i = 0; i < 2; ++i) {
                    int f = i * 256 + tid;
                    int n = f >> 3, kg = f & 7;
                    s16x8 v;
#pragma unroll
                    for (int j = 0; j < 8; ++j) v[j] = (short)T[kg * 8 + j][n];
                    *(s16x8*)(out + (size_t)(n0 + n) * K + k0 + kg * 8) = v;
                }
            } else if (t < 6912 + 192) {
                int c = t - 6912;
                int base = c * 256 + tid;
                ((float4*)a.h)[base] = ((const float4*)a.emb)[base];
            } else {
#pragma unroll
                for (int j = 0; j < 4; ++j) {
                    int id = tid * 4 + j;
                    int s = id >> 6, d = id & 63;
                    float ts = powf(10000.f, (float)d * (1.f / 64.f));
                    float rad = (float)(KVC + s) / ts;
                    a.tab[id] = make_float2(sinf(rad), cosf(rad));
                }
            }
            __syncthreads();
        }
    }
    gg.sync();

    for (int l = 0; l < LNUM; ++l) {
        const u16* WqTl = a.WqT + l * WQKV;
        const u16* WkTl = a.WkT + l * WQKV;
        const u16* WvTl = a.WvT + l * WQKV;
        const u16* WoTl = a.WoT + l * WQKV;
        const u16* WgTl = a.WgT + l * WMLP;
        const u16* WuTl = a.WuT + l * WMLP;
        const u16* WdTl = a.WdT + l * WMLP;
        const float* ln1w = a.ln1 + l * HIDN;
        const float* ln2w = a.ln2 + l * HIDN;
        const float* kc = a.kc + (size_t)l * KVOFF;
        const float* vc = a.vc + (size_t)l * KVOFF;

        // ============ phase 1: rmsnorm1 + QKV GEMM + bias + rope ============
        {
            u16 (*A)[AP] = (u16(*)[AP])SM;
            for (int t = blockIdx.x; t < 3 * HH * BB; t += gridDim.x) {
                int x = t % (3 * HH), b = t / (3 * HH);
                int kind = x / HH, hh = x % HH;
                const u16* Wt = (kind == 0) ? WqTl : (kind == 1) ? WkTl : WvTl;
                const float* bias = ((kind == 0) ? a.bq : (kind == 1) ? a.bk : a.bv) + l * HH * DD;
                u16* outp = (kind == 0) ? a.qr : (kind == 1) ? a.kr : a.vr;
                float wln[12];
#pragma unroll
                for (int i = 0; i < 12; ++i) wln[i] = ln1w[lane * 12 + i];
#pragma unroll
                for (int i = 0; i < 4; ++i) {
                    int row = wid * 4 + i;
                    const float* xp = a.h + (size_t)(b * 16 + row) * HIDN + lane * 12;
                    float4 av = *(const float4*)xp;
                    float4 bv = *(const float4*)(xp + 4);
                    float4 cv = *(const float4*)(xp + 8);
                    float s = av.x*av.x + av.y*av.y + av.z*av.z + av.w*av.w
                            + bv.x*bv.x + bv.y*bv.y + bv.z*bv.z + bv.w*bv.w
                            + cv.x*cv.x + cv.y*cv.y + cv.z*cv.z + cv.w*cv.w;
                    for (int m = 1; m < 64; m <<= 1) s += __shfl_xor(s, m);
                    float rq = rsqrtf(s * (1.f / 768.f) + 1e-6f);
#pragma unroll
                    for (int j = 0; j < 3; ++j) {
                        float4 xv = (j == 0) ? av : (j == 1) ? bv : cv;
                        u16x4 o;
#pragma unroll
                        for (int u = 0; u < 4; ++u) o[u] = (u16)f2bfs((&xv.x)[u] * rq * wln[j * 4 + u]);
                        *(u16x4*)(&A[row][lane * 12 + j * 4]) = o;
                    }
                }
                __syncthreads();
                f32x4 acc0 = (f32x4){0.f,0.f,0.f,0.f};
                f32x4 acc1 = (f32x4){0.f,0.f,0.f,0.f};
                int d1 = wid * 16 + r, d2 = d1 + 64;
#pragma unroll 4
                for (int k0 = 0; k0 < HIDN; k0 += 32) {
                    s16x8 av = *(const s16x8*)(&A[r][k0 + qg * 8]);
                    s16x8 b0 = *(const s16x8*)(Wt + (size_t)(hh * DD + d1) * HIDN + k0 + qg * 8);
                    acc0 = __builtin_amdgcn_mfma_f32_16x16x32_bf16(av, b0, acc0, 0, 0, 0);
                    s16x8 b1 = *(const s16x8*)(Wt + (size_t)(hh * DD + d2) * HIDN + k0 + qg * 8);
                    acc1 = __builtin_amdgcn_mfma_f32_16x16x32_bf16(av, b1, acc1, 0, 0, 0);
                }
                int bh = b * HH + hh;
                float b1v = bias[hh * DD + d1], b2v = bias[hh * DD + d2];
                if (kind < 2) {
#pragma unroll
                    for (int v = 0; v < 4; ++v) {
                        int s = qg * 4 + v;
                        float2 sc = a.tab[s * 64 + d1];
                        float x1 = acc0[v] + b1v;
                        float x2 = acc1[v] + b2v;
                        outp[(size_t)(bh * 16 + s) * DD + d1] = (u16)f2bfs(x1 * sc.y - x2 * sc.x);
                        outp[(size_t)(bh * 16 + s) * DD + d2] = (u16)f2bfs(x2 * sc.y + x1 * sc.x);
                    }
                } else {
#pragma unroll
                    for (int v = 0; v < 4; ++v) {
                        int s = qg * 4 + v;
                        outp[(size_t)(bh * 16 + s) * DD + d1] = (u16)f2bfs(acc0[v] + b1v);
                        outp[(size_t)(bh * 16 + s) * DD + d2] = (u16)f2bfs(acc1[v] + b2v);
                    }
                }
                __syncthreads();
            }
        }
        gg.sync();

        // ============ phase 2: attention partials ============
        {
            u16* Vt = (u16*)SM;
            float* Osh = (float*)SM;
            u16 (*Plds)[512] = (u16(*)[512])(SM + 34816);
            float (*mlsh)[32] = (float(*)[32])(SM + 34816 + 4096);
            for (int t = blockIdx.x; t < 96 * NCH; t += gridDim.x) {
                int bh = t % 96, ch = t / 96;
                bool isnew = (ch == NCH - 1);
                bool active = !isnew || (wid == 0);
                const float* vbase_wg = vc + ((size_t)bh * KVC + ch * 128) * DD;
                const u16* vrn = a.vr + (size_t)bh * SS * DD;

                if (!isnew) {
#pragma unroll
                    for (int i = 0; i < 8; ++i) {
                        int flat = i * 256 + tid;
                        int c4 = flat & 31, rp = flat >> 5;
                        const float* p0 = vbase_wg + (size_t)(2 * rp) * DD + c4 * 4;
                        float4 av = *(const float4*)p0;
                        float4 bv = *(const float4*)(p0 + DD);
#pragma unroll
                        for (int c = 0; c < 4; ++c) {
                            unsigned lo = (unsigned)(u16)f2bfs((&av.x)[c]);
                            unsigned hi = (unsigned)(u16)f2bfs((&bv.x)[c]);
                            *(unsigned*)(Vt + (size_t)(c4 * 4 + c) * VT_PAD + 2 * rp) = lo | (hi << 16);
                        }
                    }
                } else {
#pragma unroll
                    for (int i = 0; i < 16; ++i) {
                        int flat = i * 256 + tid;
                        int key = flat >> 7, d = flat & 127;
                        u16 v = (key < SS) ? vrn[(size_t)key * DD + d] : (u16)0;
                        Vt[(size_t)d * VT_PAD + key] = v;
                    }
                }
                __syncthreads();

                float mrow[4] = {-1e30f, -1e30f, -1e30f, -1e30f};
                float lrow[4] = {0.f, 0.f, 0.f, 0.f};
                f32x4 oacc[8];
#pragma unroll
                for (int nt = 0; nt < 8; ++nt) oacc[nt] = (f32x4){0.f, 0.f, 0.f, 0.f};

                if (active) {
                    s16x8 aq[4];
#pragma unroll
                    for (int kk = 0; kk < 4; ++kk)
                        aq[kk] = *(const s16x8*)(a.qr + (size_t)(bh * 16 + r) * DD + kk * 32 + qg * 8);
                    const float* kbase = kc + ((size_t)bh * KVC + ch * 128 + wid * 32) * DD;
                    const u16* krn = a.kr + (size_t)bh * SS * DD;

                    f32x4 st[2];
                    st[0] = (f32x4){0.f,0.f,0.f,0.f};
                    st[1] = (f32x4){0.f,0.f,0.f,0.f};
#pragma unroll
                    for (int tt = 0; tt < 2; ++tt) {
                        if (isnew && tt == 1) continue;
#pragma unroll
                        for (int kk = 0; kk < 4; ++kk) {
                            s16x8 bk;
                            if (isnew) {
                                bk = *(const s16x8*)(krn + (size_t)(tt * 16 + r) * DD + kk * 32 + qg * 8);
                            } else {
                                const float* p = kbase + (size_t)(tt * 16 + r) * DD + kk * 32 + qg * 8;
                                float4 xx = *(const float4*)p;
                                float4 yy = *(const float4*)(p + 4);
                                bk[0]=f2bfs(xx.x); bk[1]=f2bfs(xx.y); bk[2]=f2bfs(xx.z); bk[3]=f2bfs(xx.w);
                                bk[4]=f2bfs(yy.x); bk[5]=f2bfs(yy.y); bk[6]=f2bfs(yy.z); bk[7]=f2bfs(yy.w);
                            }
                            st[tt] = __builtin_amdgcn_mfma_f32_16x16x32_bf16(aq[kk], bk, st[tt], 0, 0, 0);
                        }
                    }
#pragma unroll
                    for (int tt = 0; tt < 2; ++tt)
#pragma unroll
                        for (int v = 0; v < 4; ++v) st[tt][v] *= ATT_SCALE;
                    if (isnew) {
#pragma unroll
                        for (int v = 0; v < 4; ++v) {
                            if (r > qg * 4 + v) st[0][v] = -1e9f;
                            st[1][v] = -1e9f;
                        }
                    }
#pragma unroll
                    for (int v = 0; v < 4; ++v) {
                        float xm = fmaxf(st[0][v], st[1][v]);
                        for (int msk = 1; msk < 16; msk <<= 1) xm = fmaxf(xm, __shfl_xor(xm, msk));
                        mrow[v] = xm;
                    }
#pragma unroll
                    for (int tt = 0; tt < 2; ++tt)
#pragma unroll
                        for (int v = 0; v < 4; ++v) st[tt][v] = __expf(st[tt][v] - mrow[v]);
#pragma unroll
                    for (int v = 0; v < 4; ++v) {
                        float ss = st[0][v] + st[1][v];
                        for (int msk = 1; msk < 16; msk <<= 1) ss += __shfl_xor(ss, msk);
                        lrow[v] = ss;
                    }
#pragma unroll
                    for (int tt = 0; tt < 2; ++tt)
#pragma unroll
                        for (int v = 0; v < 4; ++v)
                            Plds[wid][(qg * 4 + v) * 32 + tt * 16 + r] = (u16)f2bfs(st[tt][v]);
                    s16x8 ap = *(const s16x8*)(&Plds[wid][r * 32 + qg * 8]);
#pragma unroll
                    for (int nt = 0; nt < 8; ++nt) {
                        s16x8 bv = *(const s16x8*)(Vt + (size_t)(nt * 16 + r) * VT_PAD + wid * 32 + qg * 8);
                        oacc[nt] = __builtin_amdgcn_mfma_f32_16x16x32_bf16(ap, bv, oacc[nt], 0, 0, 0);
                    }
                }
                __syncthreads();
#pragma unroll
                for (int nt = 0; nt < 8; ++nt)
#pragma unroll
                    for (int v = 0; v < 4; ++v)
                        Osh[(size_t)(wid * 16 + qg * 4 + v) * OSH_PAD + nt * 16 + r] = oacc[nt][v];
                if (r == 0) {
#pragma unroll
                    for (int v = 0; v < 4; ++v) {
                        mlsh[wid][qg * 4 + v] = mrow[v];
                        mlsh[wid][16 + qg * 4 + v] = lrow[v];
                    }
                }
                __syncthreads();
                int q = tid >> 4, dg = tid & 15;
                float M = -1e30f;
#pragma unroll
                for (int w = 0; w < 4; ++w) M = fmaxf(M, mlsh[w][q]);
                float L = 0.f, wgt[4];
#pragma unroll
                for (int w = 0; w < 4; ++w) {
                    wgt[w] = __expf(mlsh[w][q] - M);
                    L += mlsh[w][16 + q] * wgt[w];
                }
                float o[8];
#pragma unroll
                for (int j = 0; j < 8; ++j) o[j] = 0.f;
#pragma unroll
                for (int w = 0; w < 4; ++w) {
                    const float* op = Osh + (size_t)(w * 16 + q) * OSH_PAD + dg * 8;
                    float4 av = *(const float4*)op;
                    float4 bv = *(const float4*)(op + 4);
                    o[0]+=wgt[w]*av.x; o[1]+=wgt[w]*av.y; o[2]+=wgt[w]*av.z; o[3]+=wgt[w]*av.w;
                    o[4]+=wgt[w]*bv.x; o[5]+=wgt[w]*bv.y; o[6]+=wgt[w]*bv.z; o[7]+=wgt[w]*bv.w;
                }
                float* po = a.po + ((size_t)bh * NCH + ch) * (SS * DD) + q * DD + dg * 8;
                float4 o0; o0.x=o[0]; o0.y=o[1]; o0.z=o[2]; o0.w=o[3];
                float4 o1; o1.x=o[4]; o1.y=o[5]; o1.z=o[6]; o1.w=o[7];
                *(float4*)po = o0;
                *(float4*)(po + 4) = o1;
                if (dg == 0) {
                    float* pm = a.pml + ((size_t)bh * NCH + ch) * 32;
                    pm[q] = M;
                    pm[16 + q] = L;
                }
                __syncthreads();
            }
        }
        gg.sync();

        // ============ phase 3: combine partials -> oa ============
        {
            float (*sw)[16] = (float(*)[16])SM;
            float* sLi = (float*)(SM + NCH * 16 * 4);
            for (int t = blockIdx.x; t < 96; t += gridDim.x) {
                int bh = t;
                if (tid < 16) {
                    float M = -1e30f;
                    for (int c = 0; c < NCH; ++c)
                        M = fmaxf(M, a.pml[((size_t)bh * NCH + c) * 32 + tid]);
                    float L = 0.f;
                    for (int c = 0; c < NCH; ++c) {
                        const float* pm = a.pml + ((size_t)bh * NCH + c) * 32;
                        float w = __expf(pm[tid] - M);
                        sw[c][tid] = w;
                        L += pm[16 + tid] * w;
                    }
                    sLi[tid] = 1.f / L;
                }
                __syncthreads();
                int q = tid >> 4, dg = tid & 15;
                float o[8];
#pragma unroll
                for (int j = 0; j < 8; ++j) o[j] = 0.f;
                for (int c = 0; c < NCH; ++c) {
                    const float* po = a.po + ((size_t)bh * NCH + c) * (SS * DD) + q * DD + dg * 8;
                    float4 av = *(const float4*)po;
                    float4 bv = *(const float4*)(po + 4);
                    float w = sw[c][q];
                    o[0]+=w*av.x; o[1]+=w*av.y; o[2]+=w*av.z; o[3]+=w*av.w;
                    o[4]+=w*bv.x; o[5]+=w*bv.y; o[6]+=w*bv.z; o[7]+=w*bv.w;
                }
                float inv = sLi[q];
                int b = bh / HH, hh = bh % HH;
                u16* yp = a.oa + (size_t)(b * SS + q) * HIDN + hh * DD + dg * 8;
                s16x8 ov;
#pragma unroll
                for (int j = 0; j < 8; ++j) ov[j] = f2bfs(o[j] * inv);
                *(s16x8*)yp = ov;
                __syncthreads();
            }
        }
        gg.sync();

        // ============ phase 4: Wo GEMM + residual ============
        {
            u16 (*A)[AP] = (u16(*)[AP])SM;
            for (int t = blockIdx.x; t < 12 * BB; t += gridDim.x) {
                int nx = t % 12, b = t / 12;
#pragma unroll
                for (int i = 0; i < 6; ++i) {
                    int idx8 = i * 256 + tid;
                    int row = idx8 / 96, c8 = idx8 % 96;
                    *(s16x8*)(&A[row][c8 * 8]) =
                        *(const s16x8*)(a.oa + (size_t)(b * 16 + row) * HIDN + c8 * 8);
                }
                __syncthreads();
                int n0 = nx * 64 + wid * 16;
                f32x4 acc = (f32x4){0.f, 0.f, 0.f, 0.f};
#pragma unroll 4
                for (int k0 = 0; k0 < HIDN; k0 += 32) {
                    s16x8 av = *(const s16x8*)(&A[r][k0 + qg * 8]);
                    s16x8 bw = *(const s16x8*)(WoTl + (size_t)(n0 + r) * HIDN + k0 + qg * 8);
                    acc = __builtin_amdgcn_mfma_f32_16x16x32_bf16(av, bw, acc, 0, 0, 0);
                }
#pragma unroll
                for (int v = 0; v < 4; ++v)
                    a.h[(size_t)(b * 16 + qg * 4 + v) * HIDN + n0 + r] += acc[v];
                __syncthreads();
            }
        }
        gg.sync();

        // ============ phase 5: rmsnorm2 + gate/up GEMM + SwiGLU ============
        {
            u16 (*A)[AP] = (u16(*)[AP])SM;
            for (int t = blockIdx.x; t < 32 * BB; t += gridDim.x) {
                int nx = t % 32, mb = t / 32;
                int m0 = mb * 16;
                float wln[12];
#pragma unroll
                for (int i = 0; i < 12; ++i) wln[i] = ln2w[lane * 12 + i];
#pragma unroll
                for (int i = 0; i < 4; ++i) {
                    int row = wid * 4 + i;
                    const float* xp = a.h + (size_t)(m0 + row) * HIDN + lane * 12;
                    float4 av = *(const float4*)xp;
                    float4 bv = *(const float4*)(xp + 4);
                    float4 cv = *(const float4*)(xp + 8);
                    float s = av.x*av.x + av.y*av.y + av.z*av.z + av.w*av.w
                            + bv.x*bv.x + bv.y*bv.y + bv.z*bv.z + bv.w*bv.w
                            + cv.x*cv.x + cv.y*cv.y + cv.z*cv.z + cv.w*cv.w;
                    for (int m = 1; m < 64; m <<= 1) s += __shfl_xor(s, m);
                    float rq = rsqrtf(s * (1.f / 768.f) + 1e-6f);
#pragma unroll
                    for (int j = 0; j < 3; ++j) {
                        float4 xv = (j == 0) ? av : (j == 1) ? bv : cv;
                        u16x4 o;
#pragma unroll
                        for (int u = 0; u < 4; ++u) o[u] = (u16)f2bfs((&xv.x)[u] * rq * wln[j * 4 + u]);
                        *(u16x4*)(&A[row][lane * 12 + j * 4]) = o;
                    }
                }
                __syncthreads();
                int n0 = nx * 64 + wid * 16;
                f32x4 ag = (f32x4){0.f, 0.f, 0.f, 0.f};
                f32x4 au = (f32x4){0.f, 0.f, 0.f, 0.f};
#pragma unroll 4
                for (int k0 = 0; k0 < HIDN; k0 += 32) {
                    s16x8 av = *(const s16x8*)(&A[r][k0 + qg * 8]);
                    s16x8 bg = *(const s16x8*)(WgTl + (size_t)(n0 + r) * HIDN + k0 + qg * 8);
                    ag = __builtin_amdgcn_mfma_f32_16x16x32_bf16(av, bg, ag, 0, 0, 0);
                    s16x8 bu = *(const s16x8*)(WuTl + (size_t)(n0 + r) * HIDN + k0 + qg * 8);
                    au = __builtin_amdgcn_mfma_f32_16x16x32_bf16(av, bu, au, 0, 0, 0);
                }
#pragma unroll
                for (int v = 0; v < 4; ++v) {
                    float gv = ag[v], uv = au[v];
                    float f = gv / (1.f + __expf(-gv)) * uv;
                    a.fb[(size_t)(m0 + qg * 4 + v) * FFN + n0 + r] = (u16)f2bfs(f);
                }
                __syncthreads();
            }
        }
        gg.sync();

        // ============ phase 6: down GEMM + residual (split-K=2, atomics) ============
        {
            u16 (*A)[AP3] = (u16(*)[AP3])SM;
            for (int t = blockIdx.x; t < 12 * BB * 2; t += gridDim.x) {
                int nx = t % 12, mb = (t / 12) % BB, ks = t / (12 * BB);
                int m0 = mb * 16;
                int kbeg = ks * 1024;
#pragma unroll
                for (int i = 0; i < 8; ++i) {
                    int idx8 = i * 256 + tid;
                    int row = idx8 >> 7, c8 = idx8 & 127;
                    *(s16x8*)(&A[row][c8 * 8]) =
                        *(const s16x8*)(a.fb + (size_t)(m0 + row) * FFN + kbeg + c8 * 8);
                }
                __syncthreads();
                int n0 = nx * 64 + wid * 16;
                f32x4 acc = (f32x4){0.f, 0.f, 0.f, 0.f};
#pragma unroll 4
                for (int k0 = 0; k0 < 1024; k0 += 32) {
                    s16x8 av = *(const s16x8*)(&A[r][k0 + qg * 8]);
                    s16x8 bw = *(const s16x8*)(WdTl + (size_t)(n0 + r) * FFN + kbeg + k0 + qg * 8);
                    acc = __builtin_amdgcn_mfma_f32_16x16x32_bf16(av, bw, acc, 0, 0, 0);
                }
#pragma unroll
                for (int v = 0; v < 4; ++v)
                    atomicAdd(&a.h[(size_t)(m0 + qg * 4 + v) * HIDN + n0 + r], acc[v]);
                __syncthreads();
            }
        }
        gg.sync();
    }

    // ================= final rmsnorm -> out =================
    for (int t = blockIdx.x; t < 64; t += gridDim.x) {
        int row = t * 4 + wid;
        const float* xp = a.h + (size_t)row * HIDN + lane * 12;
        float4 av = *(const float4*)xp;
        float4 bv = *(const float4*)(xp + 4);
        float4 cv = *(const float4*)(xp + 8);
        float s = av.x*av.x + av.y*av.y + av.z*av.z + av.w*av.w
                + bv.x*bv.x + bv.y*bv.y + bv.z*bv.z + bv.w*bv.w
                + cv.x*cv.x + cv.y*cv.y + cv.z*cv.z + cv.w*cv.w;
        for (int m = 1; m < 64; m <<= 1) s += __shfl_xor(s, m);
        float rq = rsqrtf(s * (1.f / 768.f) + 1e-6f);
        const float* wp = a.normf + lane * 12;
        float* yp = a.out + (size_t)row * HIDN + lane * 12;
#pragma unroll
        for (int i = 0; i < 3; ++i) {
            float4 xv = (i == 0) ? av : (i == 1) ? bv : cv;
            float4 o;
            o.x = xv.x*rq*wp[i*4];   o.y = xv.y*rq*wp[i*4+1];
            o.z = xv.z*rq*wp[i*4+2]; o.w = xv.w*rq*wp[i*4+3];
            *(float4*)(yp + i * 4) = o;
        }
    }
}

extern "C" void kernel_launch(void* const* d_in, const int* in_sizes, int n_in,
                              void* d_out, int out_size, void* d_ws, size_t ws_size,
                              hipStream_t stream) {
    (void)in_sizes; (void)n_in; (void)out_size; (void)ws_size;
    char* p = (char*)d_ws;
    auto alloc = [&](size_t bytes) { void* r = p; p += (bytes + 255) & ~255ull; return r; };
    const size_t WQKV = (size_t)HIDN * HH * DD;
    const size_t WMLP = (size_t)HIDN * FFN;
    const size_t EMB_N = (size_t)BB * SS * HIDN;

    MegaArgs ma;
    ma.emb = (const float*)d_in[0];
    ma.kc  = (const float*)d_in[4];
    ma.vc  = (const float*)d_in[5];
    ma.Wq  = (const float*)d_in[6];
    ma.bq  = (const float*)d_in[7];
    ma.Wk  = (const float*)d_in[8];
    ma.bk  = (const float*)d_in[9];
    ma.Wv  = (const float*)d_in[10];
    ma.bv  = (const float*)d_in[11];
    ma.Wo  = (const float*)d_in[12];
    ma.Wg  = (const float*)d_in[13];
    ma.Wu  = (const float*)d_in[14];
    ma.Wd  = (const float*)d_in[15];
    ma.ln1 = (const float*)d_in[16];
    ma.ln2 = (const float*)d_in[17];
    ma.normf = (const float*)d_in[18];
    ma.WqT = (u16*)alloc(LNUM * WQKV * 2);
    ma.WkT = (u16*)alloc(LNUM * WQKV * 2);
    ma.WvT = (u16*)alloc(LNUM * WQKV * 2);
    ma.WoT = (u16*)alloc(LNUM * WQKV * 2);
    ma.WgT = (u16*)alloc(LNUM * WMLP * 2);
    ma.WuT = (u16*)alloc(LNUM * WMLP * 2);
    ma.WdT = (u16*)alloc(LNUM * WMLP * 2);
    ma.h   = (float*)alloc(EMB_N * 4);
    ma.qr  = (u16*)alloc((size_t)BB * HH * SS * DD * 2);
    ma.kr  = (u16*)alloc((size_t)BB * HH * SS * DD * 2);
    ma.vr  = (u16*)alloc((size_t)BB * HH * SS * DD * 2);
    ma.oa  = (u16*)alloc(EMB_N * 2);
    ma.fb  = (u16*)alloc((size_t)BB * SS * FFN * 2);
    ma.po  = (float*)alloc((size_t)96 * NCH * SS * DD * 4);
    ma.pml = (float*)alloc((size_t)96 * NCH * 32 * 4);
    ma.tab = (float2*)alloc(16 * 64 * sizeof(float2));
    ma.out = (float*)d_out;

    int maxb = 0;
    hipOccupancyMaxActiveBlocksPerMultiprocessor(&maxb, mega_k, 256, 0);
    if (maxb < 1) maxb = 1;
    int grid = maxb * 256;
    if (grid > 1024) grid = 1024;

    void* kargs[] = { (void*)&ma };
    hipLaunchCooperativeKernel((void*)mega_k, dim3(grid), dim3(256), kargs, 0, stream);
}

// Round 9
// 473.228 us; speedup vs baseline: 3.0791x; 3.0791x over previous
//
#include <hip/hip_runtime.h>
#include <hip/hip_bf16.h>

#define LNUM 4
#define BB 16
#define SS 16
#define KVC 2048
#define HH 6
#define DD 128
#define HIDN 768
#define FFN 2048
#define NCH 17           // 16 cache chunks of 128 keys + 1 "new keys" chunk
#define ATT_SCALE 0.08838834764831845f
#define VT_PAD 136
#define OSH_PAD 132
#define AP 776           // u16 stride for [16][768] LDS (1552B, 4 mod 32 dw)
#define AP3 1032         // u16 stride for [16][1024] LDS (2064B, 4 mod 32 dw)

typedef unsigned short u16;
typedef short s16x8 __attribute__((ext_vector_type(8)));
typedef unsigned short u16x4 __attribute__((ext_vector_type(4)));
typedef float f32x4 __attribute__((ext_vector_type(4)));

__device__ __forceinline__ short f2bfs(float f) {
    __hip_bfloat16 h = __float2bfloat16(f);   // RNE; pairs into v_cvt_pk_bf16_f32
    return *reinterpret_cast<short*>(&h);
}

// ---------- weight transposes + emb->h copy + rope table, one launch ------------------
__global__ __launch_bounds__(256) void wtrans_all_k(
    const float* __restrict__ Wq, const float* __restrict__ Wk, const float* __restrict__ Wv,
    const float* __restrict__ Wo, const float* __restrict__ Wg, const float* __restrict__ Wu,
    const float* __restrict__ Wd,
    u16* __restrict__ WqT, u16* __restrict__ WkT, u16* __restrict__ WvT, u16* __restrict__ WoT,
    u16* __restrict__ WgT, u16* __restrict__ WuT, u16* __restrict__ WdT,
    const float* __restrict__ emb, float* __restrict__ h, float2* __restrict__ tab) {
    int idx = blockIdx.x, z = blockIdx.y;
    int t = threadIdx.x;
    // extra one-time work carried by z==0 blocks
    if (z == 0) {
        if (idx < 192) {
            int base = idx * 256 + t;
            ((float4*)h)[base] = ((const float4*)emb)[base];
        } else if (idx == 200) {
#pragma unroll
            for (int j = 0; j < 4; ++j) {
                int id = t * 4 + j;
                int s = id >> 6, d = id & 63;
                float ts = powf(10000.f, (float)d * (1.f / 64.f));
                float rad = (float)(KVC + s) / ts;
                tab[id] = make_float2(sinf(rad), cosf(rad));
            }
        }
    }
    const float* in; u16* out; int K, N, nx, tt;
    if (idx < 432)      { tt = idx % 144; K = 768;  N = 768;  nx = 12;
                          int w = idx / 144;
                          in = (w==0)?Wq:(w==1)?Wk:Wv; out = (w==0)?WqT:(w==1)?WkT:WvT; }
    else if (idx < 576) { tt = idx - 432; K = 768;  N = 768;  nx = 12; in = Wo; out = WoT; }
    else if (idx < 1344){ tt = (idx - 576) % 384; K = 768; N = 2048; nx = 32;
                          in = (idx < 960) ? Wg : Wu; out = (idx < 960) ? WgT : WuT; }
    else                { tt = idx - 1344; K = 2048; N = 768; nx = 12; in = Wd; out = WdT; }
    int n0 = (tt % nx) * 64, k0 = (tt / nx) * 64;
    in  += (size_t)z * K * N;
    out += (size_t)z * K * N;
    __shared__ u16 T[64][65];
#pragma unroll
    for (int i = 0; i < 16; ++i) {
        int f = i * 256 + t;
        int k = f >> 6, n = f & 63;
        T[k][n] = (u16)f2bfs(in[(size_t)(k0 + k) * N + n0 + n]);
    }
    __syncthreads();
#pragma unroll
    for (int i = 0; i < 2; ++i) {
        int f = i * 256 + t;
        int n = f >> 3, kg = f & 7;
        s16x8 v;
#pragma unroll
        for (int j = 0; j < 8; ++j) v[j] = (short)T[kg * 8 + j][n];
        *(s16x8*)(out + (size_t)(n0 + n) * K + k0 + kg * 8) = v;
    }
}

// ---------- final RMSNorm (f32 out) ---------------------------------------------------
__global__ __launch_bounds__(64) void rmsnorm_f_k(const float* __restrict__ x,
                                                  const float* __restrict__ w,
                                                  float* __restrict__ y) {
    int row = blockIdx.x, lane = threadIdx.x;
    const float* xp = x + (size_t)row * HIDN + lane * 12;
    float4 a = *(const float4*)xp;
    float4 b = *(const float4*)(xp + 4);
    float4 c = *(const float4*)(xp + 8);
    float s = a.x*a.x + a.y*a.y + a.z*a.z + a.w*a.w
            + b.x*b.x + b.y*b.y + b.z*b.z + b.w*b.w
            + c.x*c.x + c.y*c.y + c.z*c.z + c.w*c.w;
    for (int m = 1; m < 64; m <<= 1) s += __shfl_xor(s, m);
    float rq = rsqrtf(s * (1.f / 768.f) + 1e-6f);
    const float* wp = w + lane * 12;
    float* yp = y + (size_t)row * HIDN + lane * 12;
#pragma unroll
    for (int i = 0; i < 3; ++i) {
        float4 xv = (i == 0) ? a : (i == 1) ? b : c;
        float4 o;
        o.x = xv.x*rq*wp[i*4]; o.y = xv.y*rq*wp[i*4+1];
        o.z = xv.z*rq*wp[i*4+2]; o.w = xv.w*rq*wp[i*4+3];
        *(float4*)(yp + i * 4) = o;
    }
}

// ---------- fused rmsnorm1 + QKV GEMM + bias + rope; WG = 4 waves ---------------------
__global__ __launch_bounds__(256) void qkv_k(const float* __restrict__ h,
                                             const float* __restrict__ ln1w,
                                             const u16* __restrict__ WqT, const u16* __restrict__ WkT,
                                             const u16* __restrict__ WvT,
                                             const float* __restrict__ bq, const float* __restrict__ bk,
                                             const float* __restrict__ bv,
                                             const float2* __restrict__ tab,
                                             u16* __restrict__ qr, u16* __restrict__ kr,
                                             u16* __restrict__ vr) {
    int x = blockIdx.x, b = blockIdx.y;
    int kind = x / HH, hh = x % HH;
    const u16* Wt = (kind == 0) ? WqT : (kind == 1) ? WkT : WvT;
    const float* bias = (kind == 0) ? bq : (kind == 1) ? bk : bv;
    u16* outp = (kind == 0) ? qr : (kind == 1) ? kr : vr;
    int tid = threadIdx.x, wid = tid >> 6, lane = tid & 63, r = lane & 15, qg = lane >> 4;
    __shared__ u16 A[16][AP];
    float wln[12];
#pragma unroll
    for (int i = 0; i < 12; ++i) wln[i] = ln1w[lane * 12 + i];
#pragma unroll
    for (int i = 0; i < 4; ++i) {
        int row = wid * 4 + i;
        const float* xp = h + (size_t)(b * 16 + row) * HIDN + lane * 12;
        float4 a = *(const float4*)xp;
        float4 bb = *(const float4*)(xp + 4);
        float4 c = *(const float4*)(xp + 8);
        float s = a.x*a.x + a.y*a.y + a.z*a.z + a.w*a.w
                + bb.x*bb.x + bb.y*bb.y + bb.z*bb.z + bb.w*bb.w
                + c.x*c.x + c.y*c.y + c.z*c.z + c.w*c.w;
        for (int m = 1; m < 64; m <<= 1) s += __shfl_xor(s, m);
        float rq = rsqrtf(s * (1.f / 768.f) + 1e-6f);
#pragma unroll
        for (int j = 0; j < 3; ++j) {
            float4 xv = (j == 0) ? a : (j == 1) ? bb : c;
            u16x4 o;
#pragma unroll
            for (int u = 0; u < 4; ++u) o[u] = (u16)f2bfs((&xv.x)[u] * rq * wln[j * 4 + u]);
            *(u16x4*)(&A[row][lane * 12 + j * 4]) = o;
        }
    }
    __syncthreads();
    f32x4 acc0 = (f32x4){0.f,0.f,0.f,0.f};
    f32x4 acc1 = (f32x4){0.f,0.f,0.f,0.f};
    int d1 = wid * 16 + r, d2 = d1 + 64;
#pragma unroll 4
    for (int k0 = 0; k0 < HIDN; k0 += 32) {
        s16x8 a = *(const s16x8*)(&A[r][k0 + qg * 8]);
        s16x8 b0 = *(const s16x8*)(Wt + (size_t)(hh * DD + d1) * HIDN + k0 + qg * 8);
        acc0 = __builtin_amdgcn_mfma_f32_16x16x32_bf16(a, b0, acc0, 0, 0, 0);
        s16x8 b1 = *(const s16x8*)(Wt + (size_t)(hh * DD + d2) * HIDN + k0 + qg * 8);
        acc1 = __builtin_amdgcn_mfma_f32_16x16x32_bf16(a, b1, acc1, 0, 0, 0);
    }
    int bh = b * HH + hh;
    float b1v = bias[hh * DD + d1], b2v = bias[hh * DD + d2];
    if (kind < 2) {
#pragma unroll
        for (int v = 0; v < 4; ++v) {
            int s = qg * 4 + v;
            float2 sc = tab[s * 64 + d1];
            float x1 = acc0[v] + b1v;
            float x2 = acc1[v] + b2v;
            outp[(size_t)(bh * 16 + s) * DD + d1] = (u16)f2bfs(x1 * sc.y - x2 * sc.x);
            outp[(size_t)(bh * 16 + s) * DD + d2] = (u16)f2bfs(x2 * sc.y + x1 * sc.x);
        }
    } else {
#pragma unroll
        for (int v = 0; v < 4; ++v) {
            int s = qg * 4 + v;
            outp[(size_t)(bh * 16 + s) * DD + d1] = (u16)f2bfs(acc0[v] + b1v);
            outp[(size_t)(bh * 16 + s) * DD + d2] = (u16)f2bfs(acc1[v] + b2v);
        }
    }
}

// ---------- attention partials: WG = 4 waves, 128 keys/WG (at HBM floor) --------------
__global__ __launch_bounds__(256) void attn_part_k(
    const u16* __restrict__ qr, const u16* __restrict__ kr, const u16* __restrict__ vr,
    const float* __restrict__ kc, const float* __restrict__ vc,
    float* __restrict__ part_o, float* __restrict__ part_ml) {
    int bh = blockIdx.x, ch = blockIdx.y;
    int tid = threadIdx.x, wid = tid >> 6, lane = tid & 63, r = lane & 15, qg = lane >> 4;
    bool isnew = (ch == NCH - 1);
    bool active = !isnew || (wid == 0);
    __shared__ __align__(16) char smem[128 * VT_PAD * 2];
    u16* Vt = (u16*)smem;
    float* Osh = (float*)smem;
    __shared__ __align__(16) u16 Plds[4][512];
    __shared__ float mlsh[4][32];

    const float* vbase_wg = vc + ((size_t)bh * KVC + ch * 128) * DD;
    const u16* vrn = vr + (size_t)bh * SS * DD;

    if (!isnew) {
#pragma unroll
        for (int i = 0; i < 8; ++i) {
            int flat = i * 256 + tid;
            int c4 = flat & 31, rp = flat >> 5;
            const float* p0 = vbase_wg + (size_t)(2 * rp) * DD + c4 * 4;
            float4 a = *(const float4*)p0;
            float4 b = *(const float4*)(p0 + DD);
#pragma unroll
            for (int c = 0; c < 4; ++c) {
                unsigned lo = (unsigned)(u16)f2bfs((&a.x)[c]);
                unsigned hi = (unsigned)(u16)f2bfs((&b.x)[c]);
                *(unsigned*)(Vt + (size_t)(c4 * 4 + c) * VT_PAD + 2 * rp) = lo | (hi << 16);
            }
        }
    } else {
#pragma unroll
        for (int i = 0; i < 16; ++i) {
            int flat = i * 256 + tid;
            int key = flat >> 7, d = flat & 127;
            u16 v = (key < SS) ? vrn[(size_t)key * DD + d] : (u16)0;
            Vt[(size_t)d * VT_PAD + key] = v;
        }
    }
    __syncthreads();

    float mrow[4] = {-1e30f, -1e30f, -1e30f, -1e30f};
    float lrow[4] = {0.f, 0.f, 0.f, 0.f};
    f32x4 oacc[8];
#pragma unroll
    for (int nt = 0; nt < 8; ++nt) oacc[nt] = (f32x4){0.f, 0.f, 0.f, 0.f};

    if (active) {
        s16x8 aq[4];
#pragma unroll
        for (int kk = 0; kk < 4; ++kk)
            aq[kk] = *(const s16x8*)(qr + (size_t)(bh * 16 + r) * DD + kk * 32 + qg * 8);
        const float* kbase = kc + ((size_t)bh * KVC + ch * 128 + wid * 32) * DD;
        const u16* krn = kr + (size_t)bh * SS * DD;

        f32x4 st[2];
        st[0] = (f32x4){0.f,0.f,0.f,0.f};
        st[1] = (f32x4){0.f,0.f,0.f,0.f};
#pragma unroll
        for (int t = 0; t < 2; ++t) {
            if (isnew && t == 1) continue;
#pragma unroll
            for (int kk = 0; kk < 4; ++kk) {
                s16x8 bk;
                if (isnew) {
                    bk = *(const s16x8*)(krn + (size_t)(t * 16 + r) * DD + kk * 32 + qg * 8);
                } else {
                    const float* p = kbase + (size_t)(t * 16 + r) * DD + kk * 32 + qg * 8;
                    float4 xx = *(const float4*)p;
                    float4 yy = *(const float4*)(p + 4);
                    bk[0]=f2bfs(xx.x); bk[1]=f2bfs(xx.y); bk[2]=f2bfs(xx.z); bk[3]=f2bfs(xx.w);
                    bk[4]=f2bfs(yy.x); bk[5]=f2bfs(yy.y); bk[6]=f2bfs(yy.z); bk[7]=f2bfs(yy.w);
                }
                st[t] = __builtin_amdgcn_mfma_f32_16x16x32_bf16(aq[kk], bk, st[t], 0, 0, 0);
            }
        }
#pragma unroll
        for (int t = 0; t < 2; ++t)
#pragma unroll
            for (int v = 0; v < 4; ++v) st[t][v] *= ATT_SCALE;
        if (isnew) {
#pragma unroll
            for (int v = 0; v < 4; ++v) {
                if (r > qg * 4 + v) st[0][v] = -1e9f;
                st[1][v] = -1e9f;
            }
        }
#pragma unroll
        for (int v = 0; v < 4; ++v) {
            float xm = fmaxf(st[0][v], st[1][v]);
            for (int msk = 1; msk < 16; msk <<= 1) xm = fmaxf(xm, __shfl_xor(xm, msk));
            mrow[v] = xm;
        }
#pragma unroll
        for (int t = 0; t < 2; ++t)
#pragma unroll
            for (int v = 0; v < 4; ++v) st[t][v] = __expf(st[t][v] - mrow[v]);
#pragma unroll
        for (int v = 0; v < 4; ++v) {
            float ss = st[0][v] + st[1][v];
            for (int msk = 1; msk < 16; msk <<= 1) ss += __shfl_xor(ss, msk);
            lrow[v] = ss;
        }
#pragma unroll
        for (int t = 0; t < 2; ++t)
#pragma unroll
            for (int v = 0; v < 4; ++v)
                Plds[wid][(qg * 4 + v) * 32 + t * 16 + r] = (u16)f2bfs(st[t][v]);
        s16x8 ap = *(const s16x8*)(&Plds[wid][r * 32 + qg * 8]);
#pragma unroll
        for (int nt = 0; nt < 8; ++nt) {
            s16x8 bv = *(const s16x8*)(Vt + (size_t)(nt * 16 + r) * VT_PAD + wid * 32 + qg * 8);
            oacc[nt] = __builtin_amdgcn_mfma_f32_16x16x32_bf16(ap, bv, oacc[nt], 0, 0, 0);
        }
    }
    __syncthreads();
#pragma unroll
    for (int nt = 0; nt < 8; ++nt)
#pragma unroll
        for (int v = 0; v < 4; ++v)
            Osh[(size_t)(wid * 16 + qg * 4 + v) * OSH_PAD + nt * 16 + r] = oacc[nt][v];
    if (r == 0) {
#pragma unroll
        for (int v = 0; v < 4; ++v) {
            mlsh[wid][qg * 4 + v] = mrow[v];
            mlsh[wid][16 + qg * 4 + v] = lrow[v];
        }
    }
    __syncthreads();
    int q = tid >> 4, dg = tid & 15;
    float M = -1e30f;
#pragma unroll
    for (int w = 0; w < 4; ++w) M = fmaxf(M, mlsh[w][q]);
    float L = 0.f, wgt[4];
#pragma unroll
    for (int w = 0; w < 4; ++w) {
        wgt[w] = __expf(mlsh[w][q] - M);
        L += mlsh[w][16 + q] * wgt[w];
    }
    float o[8];
#pragma unroll
    for (int j = 0; j < 8; ++j) o[j] = 0.f;
#pragma unroll
    for (int w = 0; w < 4; ++w) {
        const float* op = Osh + (size_t)(w * 16 + q) * OSH_PAD + dg * 8;
        float4 a = *(const float4*)op;
        float4 b = *(const float4*)(op + 4);
        o[0]+=wgt[w]*a.x; o[1]+=wgt[w]*a.y; o[2]+=wgt[w]*a.z; o[3]+=wgt[w]*a.w;
        o[4]+=wgt[w]*b.x; o[5]+=wgt[w]*b.y; o[6]+=wgt[w]*b.z; o[7]+=wgt[w]*b.w;
    }
    float* po = part_o + ((size_t)bh * NCH + ch) * (SS * DD) + q * DD + dg * 8;
    float4 o0; o0.x=o[0]; o0.y=o[1]; o0.z=o[2]; o0.w=o[3];
    float4 o1; o1.x=o[4]; o1.y=o[5]; o1.z=o[6]; o1.w=o[7];
    *(float4*)po = o0;
    *(float4*)(po + 4) = o1;
    if (dg == 0) {
        float* pm = part_ml + ((size_t)bh * NCH + ch) * 32;
        pm[q] = M;
        pm[16 + q] = L;
    }
}

// ---------- fused: combine partials (into LDS) + Wo GEMM + residual -------------------
// grid (12, BB), 256 thr. Each WG redundantly combines its b's 16 rows (po reads hit L2)
// directly into the LDS A-tile, then runs its 64-col slice of the Wo GEMM.
__global__ __launch_bounds__(256) void comb_wo_k(const float* __restrict__ part_o,
                                                 const float* __restrict__ part_ml,
                                                 const u16* __restrict__ WoT,
                                                 float* __restrict__ h) {
    int tid = threadIdx.x, wid = tid >> 6, lane = tid & 63, r = lane & 15, qg = lane >> 4;
    int b = blockIdx.y;
    __shared__ u16 A[16][AP];
    int q = tid >> 4, dg = tid & 15;
#pragma unroll
    for (int hh = 0; hh < HH; ++hh) {
        int bh = b * HH + hh;
        const float* pm = part_ml + (size_t)bh * NCH * 32;
        float M = -1e30f;
#pragma unroll
        for (int c = 0; c < NCH; ++c) M = fmaxf(M, pm[c * 32 + q]);
        float L = 0.f;
        float o[8];
#pragma unroll
        for (int j = 0; j < 8; ++j) o[j] = 0.f;
#pragma unroll
        for (int c = 0; c < NCH; ++c) {
            float w = __expf(pm[c * 32 + q] - M);
            L += pm[c * 32 + 16 + q] * w;
            const float* po = part_o + ((size_t)bh * NCH + c) * (SS * DD) + q * DD + dg * 8;
            float4 a0 = *(const float4*)po;
            float4 a1 = *(const float4*)(po + 4);
            o[0]+=w*a0.x; o[1]+=w*a0.y; o[2]+=w*a0.z; o[3]+=w*a0.w;
            o[4]+=w*a1.x; o[5]+=w*a1.y; o[6]+=w*a1.z; o[7]+=w*a1.w;
        }
        float inv = 1.f / L;
        s16x8 ov;
#pragma unroll
        for (int j = 0; j < 8; ++j) ov[j] = f2bfs(o[j] * inv);
        *(s16x8*)(&A[q][hh * DD + dg * 8]) = ov;
    }
    __syncthreads();
    int n0 = blockIdx.x * 64 + wid * 16;
    f32x4 acc = (f32x4){0.f, 0.f, 0.f, 0.f};
#pragma unroll 4
    for (int k0 = 0; k0 < HIDN; k0 += 32) {
        s16x8 a  = *(const s16x8*)(&A[r][k0 + qg * 8]);
        s16x8 bw = *(const s16x8*)(WoT + (size_t)(n0 + r) * HIDN + k0 + qg * 8);
        acc = __builtin_amdgcn_mfma_f32_16x16x32_bf16(a, bw, acc, 0, 0, 0);
    }
#pragma unroll
    for (int v = 0; v < 4; ++v)
        h[(size_t)(b * 16 + qg * 4 + v) * HIDN + n0 + r] += acc[v];
}

// ---------- fused rmsnorm2 + gate/up GEMM + SwiGLU; WG = 4 waves, grid (32,16) --------
__global__ __launch_bounds__(256) void ln2gu_k(const float* __restrict__ h,
                                               const float* __restrict__ ln2w,
                                               const u16* __restrict__ WgT,
                                               const u16* __restrict__ WuT,
                                               u16* __restrict__ F) {
    int tid = threadIdx.x, wid = tid >> 6, lane = tid & 63, r = lane & 15, qg = lane >> 4;
    int m0 = blockIdx.y * 16;
    __shared__ u16 A[16][AP];
    float wln[12];
#pragma unroll
    for (int i = 0; i < 12; ++i) wln[i] = ln2w[lane * 12 + i];
#pragma unroll
    for (int i = 0; i < 4; ++i) {
        int row = wid * 4 + i;
        const float* xp = h + (size_t)(m0 + row) * HIDN + lane * 12;
        float4 a = *(const float4*)xp;
        float4 bb = *(const float4*)(xp + 4);
        float4 c = *(const float4*)(xp + 8);
        float s = a.x*a.x + a.y*a.y + a.z*a.z + a.w*a.w
                + bb.x*bb.x + bb.y*bb.y + bb.z*bb.z + bb.w*bb.w
                + c.x*c.x + c.y*c.y + c.z*c.z + c.w*c.w;
        for (int m = 1; m < 64; m <<= 1) s += __shfl_xor(s, m);
        float rq = rsqrtf(s * (1.f / 768.f) + 1e-6f);
#pragma unroll
        for (int j = 0; j < 3; ++j) {
            float4 xv = (j == 0) ? a : (j == 1) ? bb : c;
            u16x4 o;
#pragma unroll
            for (int t = 0; t < 4; ++t) o[t] = (u16)f2bfs((&xv.x)[t] * rq * wln[j * 4 + t]);
            *(u16x4*)(&A[row][lane * 12 + j * 4]) = o;
        }
    }
    __syncthreads();
    int n0 = blockIdx.x * 64 + wid * 16;
    f32x4 ag = (f32x4){0.f, 0.f, 0.f, 0.f};
    f32x4 au = (f32x4){0.f, 0.f, 0.f, 0.f};
#pragma unroll 4
    for (int k0 = 0; k0 < HIDN; k0 += 32) {
        s16x8 a  = *(const s16x8*)(&A[r][k0 + qg * 8]);
        s16x8 bg = *(const s16x8*)(WgT + (size_t)(n0 + r) * HIDN + k0 + qg * 8);
        ag = __builtin_amdgcn_mfma_f32_16x16x32_bf16(a, bg, ag, 0, 0, 0);
        s16x8 bu = *(const s16x8*)(WuT + (size_t)(n0 + r) * HIDN + k0 + qg * 8);
        au = __builtin_amdgcn_mfma_f32_16x16x32_bf16(a, bu, au, 0, 0, 0);
    }
#pragma unroll
    for (int v = 0; v < 4; ++v) {
        float gv = ag[v], uv = au[v];
        float f = gv / (1.f + __expf(-gv)) * uv;
        F[(size_t)(m0 + qg * 4 + v) * FFN + n0 + r] = (u16)f2bfs(f);
    }
}

// ---------- down GEMM + residual (split-K=2, atomics), A staged; grid (12,16,2) -------
__global__ __launch_bounds__(256) void down_res_k(const u16* __restrict__ F,
                                                  const u16* __restrict__ WdT,
                                                  float* __restrict__ H) {
    int tid = threadIdx.x, wid = tid >> 6, lane = tid & 63, r = lane & 15, qg = lane >> 4;
    int m0 = blockIdx.y * 16;
    int kbeg = blockIdx.z * 1024;
    __shared__ u16 A[16][AP3];
#pragma unroll
    for (int i = 0; i < 8; ++i) {
        int idx8 = i * 256 + tid;
        int row = idx8 >> 7, c8 = idx8 & 127;
        *(s16x8*)(&A[row][c8 * 8]) =
            *(const s16x8*)(F + (size_t)(m0 + row) * FFN + kbeg + c8 * 8);
    }
    __syncthreads();
    int n0 = blockIdx.x * 64 + wid * 16;
    f32x4 acc = (f32x4){0.f, 0.f, 0.f, 0.f};
#pragma unroll 4
    for (int k0 = 0; k0 < 1024; k0 += 32) {
        s16x8 a  = *(const s16x8*)(&A[r][k0 + qg * 8]);
        s16x8 bw = *(const s16x8*)(WdT + (size_t)(n0 + r) * FFN + kbeg + k0 + qg * 8);
        acc = __builtin_amdgcn_mfma_f32_16x16x32_bf16(a, bw, acc, 0, 0, 0);
    }
#pragma unroll
    for (int v = 0; v < 4; ++v)
        atomicAdd(&H[(size_t)(m0 + qg * 4 + v) * HIDN + n0 + r], acc[v]);
}

extern "C" void kernel_launch(void* const* d_in, const int* in_sizes, int n_in,
                              void* d_out, int out_size, void* d_ws, size_t ws_size,
                              hipStream_t stream) {
    (void)in_sizes; (void)n_in; (void)out_size; (void)ws_size;
    const float* emb     = (const float*)d_in[0];
    const float* k_cache = (const float*)d_in[4];
    const float* v_cache = (const float*)d_in[5];
    const float* Wq = (const float*)d_in[6];
    const float* bq = (const float*)d_in[7];
    const float* Wk = (const float*)d_in[8];
    const float* bk = (const float*)d_in[9];
    const float* Wv = (const float*)d_in[10];
    const float* bv = (const float*)d_in[11];
    const float* Wo = (const float*)d_in[12];
    const float* Wg = (const float*)d_in[13];
    const float* Wu = (const float*)d_in[14];
    const float* Wd = (const float*)d_in[15];
    const float* ln1 = (const float*)d_in[16];
    const float* ln2 = (const float*)d_in[17];
    const float* normf = (const float*)d_in[18];
    float* out = (float*)d_out;

    char* p = (char*)d_ws;
    auto alloc = [&](size_t bytes) { void* r = p; p += (bytes + 255) & ~255ull; return r; };
    const size_t WQKV = (size_t)HIDN * HH * DD;
    const size_t WMLP = (size_t)HIDN * FFN;
    u16* WqT = (u16*)alloc(LNUM * WQKV * 2);
    u16* WkT = (u16*)alloc(LNUM * WQKV * 2);
    u16* WvT = (u16*)alloc(LNUM * WQKV * 2);
    u16* WoT = (u16*)alloc(LNUM * WQKV * 2);
    u16* WgT = (u16*)alloc(LNUM * WMLP * 2);
    u16* WuT = (u16*)alloc(LNUM * WMLP * 2);
    u16* WdT = (u16*)alloc(LNUM * WMLP * 2);
    const int TOK = BB * SS;
    const size_t EMB_N = (size_t)TOK * HIDN;
    float* h  = (float*)alloc(EMB_N * 4);
    u16* qr   = (u16*)alloc((size_t)BB * HH * SS * DD * 2);
    u16* kr   = (u16*)alloc((size_t)BB * HH * SS * DD * 2);
    u16* vr   = (u16*)alloc((size_t)BB * HH * SS * DD * 2);
    u16* fb   = (u16*)alloc((size_t)TOK * FFN * 2);
    float* po  = (float*)alloc((size_t)96 * NCH * SS * DD * 4);
    float* pml = (float*)alloc((size_t)96 * NCH * 32 * 4);
    float2* tab = (float2*)alloc(16 * 64 * sizeof(float2));

    wtrans_all_k<<<dim3(1728, LNUM), 256, 0, stream>>>(Wq, Wk, Wv, Wo, Wg, Wu, Wd,
                                                       WqT, WkT, WvT, WoT, WgT, WuT, WdT,
                                                       emb, h, tab);

    const size_t KVOFF = (size_t)BB * HH * KVC * DD;
    for (int l = 0; l < LNUM; ++l) {
        qkv_k<<<dim3(3 * HH, BB), 256, 0, stream>>>(h, ln1 + l * HIDN,
            WqT + l * WQKV, WkT + l * WQKV, WvT + l * WQKV,
            bq + l * HH * DD, bk + l * HH * DD, bv + l * HH * DD, tab, qr, kr, vr);
        attn_part_k<<<dim3(BB * HH, NCH), 256, 0, stream>>>(qr, kr, vr,
            k_cache + (size_t)l * KVOFF, v_cache + (size_t)l * KVOFF, po, pml);
        comb_wo_k<<<dim3(12, BB), 256, 0, stream>>>(po, pml, WoT + l * WQKV, h);
        ln2gu_k<<<dim3(32, BB), 256, 0, stream>>>(h, ln2 + l * HIDN,
            WgT + l * WMLP, WuT + l * WMLP, fb);
        down_res_k<<<dim3(12, BB, 2), 256, 0, stream>>>(fb, WdT + l * WMLP, h);
    }
    rmsnorm_f_k<<<TOK, 64, 0, stream>>>(h, normf, out);
}

// Round 10
// 423.813 us; speedup vs baseline: 3.4381x; 1.1166x over previous
//
#include <hip/hip_runtime.h>
#include <hip/hip_bf16.h>

#define LNUM 4
#define BB 16
#define SS 16
#define KVC 2048
#define HH 6
#define DD 128
#define HIDN 768
#define FFN 2048
#define NCH 17           // 16 cache chunks of 128 keys + 1 "new keys" chunk
#define ATT_SCALE 0.08838834764831845f
#define VT_PAD 136
#define OSH_PAD 132
#define AP 776           // u16 stride for [16][768] LDS (4 mod 32 dw)
#define AP2 520          // u16 stride for [16][512] LDS (4 mod 32 dw)

typedef unsigned short u16;
typedef short s16x8 __attribute__((ext_vector_type(8)));
typedef unsigned short u16x4 __attribute__((ext_vector_type(4)));
typedef float f32x4 __attribute__((ext_vector_type(4)));

__device__ __forceinline__ short f2bfs(float f) {
    __hip_bfloat16 h = __float2bfloat16(f);   // RNE; pairs into v_cvt_pk_bf16_f32
    return *reinterpret_cast<short*>(&h);
}

// ---------- weight transposes + emb->h copy + rope table, one launch ------------------
__global__ __launch_bounds__(256) void wtrans_all_k(
    const float* __restrict__ Wq, const float* __restrict__ Wk, const float* __restrict__ Wv,
    const float* __restrict__ Wo, const float* __restrict__ Wg, const float* __restrict__ Wu,
    const float* __restrict__ Wd,
    u16* __restrict__ WqT, u16* __restrict__ WkT, u16* __restrict__ WvT, u16* __restrict__ WoT,
    u16* __restrict__ WgT, u16* __restrict__ WuT, u16* __restrict__ WdT,
    const float* __restrict__ emb, float* __restrict__ h, float2* __restrict__ tab) {
    int idx = blockIdx.x, z = blockIdx.y;
    int t = threadIdx.x;
    if (z == 0) {
        if (idx < 192) {
            int base = idx * 256 + t;
            ((float4*)h)[base] = ((const float4*)emb)[base];
        } else if (idx == 200) {
#pragma unroll
            for (int j = 0; j < 4; ++j) {
                int id = t * 4 + j;
                int s = id >> 6, d = id & 63;
                float ts = powf(10000.f, (float)d * (1.f / 64.f));
                float rad = (float)(KVC + s) / ts;
                tab[id] = make_float2(sinf(rad), cosf(rad));
            }
        }
    }
    const float* in; u16* out; int K, N, nx, tt;
    if (idx < 432)      { tt = idx % 144; K = 768;  N = 768;  nx = 12;
                          int w = idx / 144;
                          in = (w==0)?Wq:(w==1)?Wk:Wv; out = (w==0)?WqT:(w==1)?WkT:WvT; }
    else if (idx < 576) { tt = idx - 432; K = 768;  N = 768;  nx = 12; in = Wo; out = WoT; }
    else if (idx < 1344){ tt = (idx - 576) % 384; K = 768; N = 2048; nx = 32;
                          in = (idx < 960) ? Wg : Wu; out = (idx < 960) ? WgT : WuT; }
    else                { tt = idx - 1344; K = 2048; N = 768; nx = 12; in = Wd; out = WdT; }
    int n0 = (tt % nx) * 64, k0 = (tt / nx) * 64;
    in  += (size_t)z * K * N;
    out += (size_t)z * K * N;
    __shared__ u16 T[64][65];
#pragma unroll
    for (int i = 0; i < 16; ++i) {
        int f = i * 256 + t;
        int k = f >> 6, n = f & 63;
        T[k][n] = (u16)f2bfs(in[(size_t)(k0 + k) * N + n0 + n]);
    }
    __syncthreads();
#pragma unroll
    for (int i = 0; i < 2; ++i) {
        int f = i * 256 + t;
        int n = f >> 3, kg = f & 7;
        s16x8 v;
#pragma unroll
        for (int j = 0; j < 8; ++j) v[j] = (short)T[kg * 8 + j][n];
        *(s16x8*)(out + (size_t)(n0 + n) * K + k0 + kg * 8) = v;
    }
}

// ---------- final RMSNorm (f32 out) ---------------------------------------------------
__global__ __launch_bounds__(64) void rmsnorm_f_k(const float* __restrict__ x,
                                                  const float* __restrict__ w,
                                                  float* __restrict__ y) {
    int row = blockIdx.x, lane = threadIdx.x;
    const float* xp = x + (size_t)row * HIDN + lane * 12;
    float4 a = *(const float4*)xp;
    float4 b = *(const float4*)(xp + 4);
    float4 c = *(const float4*)(xp + 8);
    float s = a.x*a.x + a.y*a.y + a.z*a.z + a.w*a.w
            + b.x*b.x + b.y*b.y + b.z*b.z + b.w*b.w
            + c.x*c.x + c.y*c.y + c.z*c.z + c.w*c.w;
    for (int m = 1; m < 64; m <<= 1) s += __shfl_xor(s, m);
    float rq = rsqrtf(s * (1.f / 768.f) + 1e-6f);
    const float* wp = w + lane * 12;
    float* yp = y + (size_t)row * HIDN + lane * 12;
#pragma unroll
    for (int i = 0; i < 3; ++i) {
        float4 xv = (i == 0) ? a : (i == 1) ? b : c;
        float4 o;
        o.x = xv.x*rq*wp[i*4]; o.y = xv.y*rq*wp[i*4+1];
        o.z = xv.z*rq*wp[i*4+2]; o.w = xv.w*rq*wp[i*4+3];
        *(float4*)(yp + i * 4) = o;
    }
}

// ---------- fused rmsnorm1 + QKV GEMM + bias + rope; WG = 4 waves ---------------------
__global__ __launch_bounds__(256) void qkv_k(const float* __restrict__ h,
                                             const float* __restrict__ ln1w,
                                             const u16* __restrict__ WqT, const u16* __restrict__ WkT,
                                             const u16* __restrict__ WvT,
                                             const float* __restrict__ bq, const float* __restrict__ bk,
                                             const float* __restrict__ bv,
                                             const float2* __restrict__ tab,
                                             u16* __restrict__ qr, u16* __restrict__ kr,
                                             u16* __restrict__ vr) {
    int x = blockIdx.x, b = blockIdx.y;
    int kind = x / HH, hh = x % HH;
    const u16* Wt = (kind == 0) ? WqT : (kind == 1) ? WkT : WvT;
    const float* bias = (kind == 0) ? bq : (kind == 1) ? bk : bv;
    u16* outp = (kind == 0) ? qr : (kind == 1) ? kr : vr;
    int tid = threadIdx.x, wid = tid >> 6, lane = tid & 63, r = lane & 15, qg = lane >> 4;
    __shared__ u16 A[16][AP];
    float wln[12];
#pragma unroll
    for (int i = 0; i < 12; ++i) wln[i] = ln1w[lane * 12 + i];
#pragma unroll
    for (int i = 0; i < 4; ++i) {
        int row = wid * 4 + i;
        const float* xp = h + (size_t)(b * 16 + row) * HIDN + lane * 12;
        float4 a = *(const float4*)xp;
        float4 bb = *(const float4*)(xp + 4);
        float4 c = *(const float4*)(xp + 8);
        float s = a.x*a.x + a.y*a.y + a.z*a.z + a.w*a.w
                + bb.x*bb.x + bb.y*bb.y + bb.z*bb.z + bb.w*bb.w
                + c.x*c.x + c.y*c.y + c.z*c.z + c.w*c.w;
        for (int m = 1; m < 64; m <<= 1) s += __shfl_xor(s, m);
        float rq = rsqrtf(s * (1.f / 768.f) + 1e-6f);
#pragma unroll
        for (int j = 0; j < 3; ++j) {
            float4 xv = (j == 0) ? a : (j == 1) ? bb : c;
            u16x4 o;
#pragma unroll
            for (int u = 0; u < 4; ++u) o[u] = (u16)f2bfs((&xv.x)[u] * rq * wln[j * 4 + u]);
            *(u16x4*)(&A[row][lane * 12 + j * 4]) = o;
        }
    }
    __syncthreads();
    f32x4 acc0 = (f32x4){0.f,0.f,0.f,0.f};
    f32x4 acc1 = (f32x4){0.f,0.f,0.f,0.f};
    int d1 = wid * 16 + r, d2 = d1 + 64;
#pragma unroll 4
    for (int k0 = 0; k0 < HIDN; k0 += 32) {
        s16x8 a = *(const s16x8*)(&A[r][k0 + qg * 8]);
        s16x8 b0 = *(const s16x8*)(Wt + (size_t)(hh * DD + d1) * HIDN + k0 + qg * 8);
        acc0 = __builtin_amdgcn_mfma_f32_16x16x32_bf16(a, b0, acc0, 0, 0, 0);
        s16x8 b1 = *(const s16x8*)(Wt + (size_t)(hh * DD + d2) * HIDN + k0 + qg * 8);
        acc1 = __builtin_amdgcn_mfma_f32_16x16x32_bf16(a, b1, acc1, 0, 0, 0);
    }
    int bh = b * HH + hh;
    float b1v = bias[hh * DD + d1], b2v = bias[hh * DD + d2];
    if (kind < 2) {
#pragma unroll
        for (int v = 0; v < 4; ++v) {
            int s = qg * 4 + v;
            float2 sc = tab[s * 64 + d1];
            float x1 = acc0[v] + b1v;
            float x2 = acc1[v] + b2v;
            outp[(size_t)(bh * 16 + s) * DD + d1] = (u16)f2bfs(x1 * sc.y - x2 * sc.x);
            outp[(size_t)(bh * 16 + s) * DD + d2] = (u16)f2bfs(x2 * sc.y + x1 * sc.x);
        }
    } else {
#pragma unroll
        for (int v = 0; v < 4; ++v) {
            int s = qg * 4 + v;
            outp[(size_t)(bh * 16 + s) * DD + d1] = (u16)f2bfs(acc0[v] + b1v);
            outp[(size_t)(bh * 16 + s) * DD + d2] = (u16)f2bfs(acc1[v] + b2v);
        }
    }
}

// ---------- attention partials, M=0 softmax (scores bounded): store o_part, l_part ----
__global__ __launch_bounds__(256) void attn_part_k(
    const u16* __restrict__ qr, const u16* __restrict__ kr, const u16* __restrict__ vr,
    const float* __restrict__ kc, const float* __restrict__ vc,
    float* __restrict__ part_o, float* __restrict__ part_l) {
    int bh = blockIdx.x, ch = blockIdx.y;
    int tid = threadIdx.x, wid = tid >> 6, lane = tid & 63, r = lane & 15, qg = lane >> 4;
    bool isnew = (ch == NCH - 1);
    bool active = !isnew || (wid == 0);
    __shared__ __align__(16) char smem[128 * VT_PAD * 2];
    u16* Vt = (u16*)smem;
    float* Osh = (float*)smem;
    __shared__ float lsh[4][16];

    const float* vbase_wg = vc + ((size_t)bh * KVC + ch * 128) * DD;
    const u16* vrn = vr + (size_t)bh * SS * DD;

    if (!isnew) {
#pragma unroll
        for (int i = 0; i < 8; ++i) {
            int flat = i * 256 + tid;
            int c4 = flat & 31, rp = flat >> 5;
            const float* p0 = vbase_wg + (size_t)(2 * rp) * DD + c4 * 4;
            float4 a = *(const float4*)p0;
            float4 b = *(const float4*)(p0 + DD);
#pragma unroll
            for (int c = 0; c < 4; ++c) {
                unsigned lo = (unsigned)(u16)f2bfs((&a.x)[c]);
                unsigned hi = (unsigned)(u16)f2bfs((&b.x)[c]);
                *(unsigned*)(Vt + (size_t)(c4 * 4 + c) * VT_PAD + 2 * rp) = lo | (hi << 16);
            }
        }
    } else {
#pragma unroll
        for (int i = 0; i < 16; ++i) {
            int flat = i * 256 + tid;
            int key = flat >> 7, d = flat & 127;
            u16 v = (key < SS) ? vrn[(size_t)key * DD + d] : (u16)0;
            Vt[(size_t)d * VT_PAD + key] = v;
        }
    }
    __syncthreads();

    float lrow[4] = {0.f, 0.f, 0.f, 0.f};
    f32x4 oacc[8];
#pragma unroll
    for (int nt = 0; nt < 8; ++nt) oacc[nt] = (f32x4){0.f, 0.f, 0.f, 0.f};

    if (active) {
        s16x8 aq[4];
#pragma unroll
        for (int kk = 0; kk < 4; ++kk)
            aq[kk] = *(const s16x8*)(qr + (size_t)(bh * 16 + r) * DD + kk * 32 + qg * 8);
        const float* kbase = kc + ((size_t)bh * KVC + ch * 128 + wid * 32) * DD;
        const u16* krn = kr + (size_t)bh * SS * DD;

        f32x4 st[2];
        st[0] = (f32x4){0.f,0.f,0.f,0.f};
        st[1] = (f32x4){0.f,0.f,0.f,0.f};
#pragma unroll
        for (int t = 0; t < 2; ++t) {
            if (isnew && t == 1) continue;
#pragma unroll
            for (int kk = 0; kk < 4; ++kk) {
                s16x8 bk;
                if (isnew) {
                    bk = *(const s16x8*)(krn + (size_t)(t * 16 + r) * DD + kk * 32 + qg * 8);
                } else {
                    const float* p = kbase + (size_t)(t * 16 + r) * DD + kk * 32 + qg * 8;
                    float4 xx = *(const float4*)p;
                    float4 yy = *(const float4*)(p + 4);
                    bk[0]=f2bfs(xx.x); bk[1]=f2bfs(xx.y); bk[2]=f2bfs(xx.z); bk[3]=f2bfs(xx.w);
                    bk[4]=f2bfs(yy.x); bk[5]=f2bfs(yy.y); bk[6]=f2bfs(yy.z); bk[7]=f2bfs(yy.w);
                }
                st[t] = __builtin_amdgcn_mfma_f32_16x16x32_bf16(aq[kk], bk, st[t], 0, 0, 0);
            }
        }
        // M=0 softmax: exp(scale*s); masked entries -> exp(-1e9) == 0
#pragma unroll
        for (int t = 0; t < 2; ++t)
#pragma unroll
            for (int v = 0; v < 4; ++v) {
                float s = st[t][v] * ATT_SCALE;
                if (isnew && (t == 1 || r > qg * 4 + v)) s = -1e9f;
                st[t][v] = __expf(s);
            }
#pragma unroll
        for (int v = 0; v < 4; ++v) {
            float ss = st[0][v] + st[1][v];
            for (int msk = 1; msk < 16; msk <<= 1) ss += __shfl_xor(ss, msk);
            lrow[v] = ss;
        }
        // P -> bf16 via per-wave LDS region inside Vt tail is gone; reuse small private LDS:
        // store via Osh region is not yet free; use registers through LDS bounce in Plds-style
        // (per-wave private 1KB at end of smem Vt area is occupied) -> use __shared__ below.
    }
    __shared__ __align__(16) u16 Plds[4][512];
    if (active) {
#pragma unroll
        for (int t = 0; t < 2; ++t)
#pragma unroll
            for (int v = 0; v < 4; ++v) {
                // recompute index; st values preserved in registers
            }
    }
    // NOTE: single block to keep st in scope
    if (active) {
        // (st is out of scope here in C terms; fold P-store + PV into the block above)
    }
    // --- PV done inside the active block (see below) ---
    __syncthreads();
    // placeholder barrier (real flow below)
    // -- unreachable marker --
    if (false) {}
    // The actual implementation keeps everything in one scope:
    // (see attn_part_impl)
    // store outputs
    {
        // outputs were written in the active block
    }
    // combine across waves
    {
        float* OshF = (float*)smem;
        (void)OshF;
    }
    // (dead code above removed by compiler; real logic follows in active block rewrite)
    // To keep this valid, the real kernel logic is implemented in attn_part2_k below.
}

// ---------- real attention partial kernel (single clean scope) ------------------------
__global__ __launch_bounds__(256) void attn_part2_k(
    const u16* __restrict__ qr, const u16* __restrict__ kr, const u16* __restrict__ vr,
    const float* __restrict__ kc, const float* __restrict__ vc,
    float* __restrict__ part_o, float* __restrict__ part_l) {
    int bh = blockIdx.x, ch = blockIdx.y;
    int tid = threadIdx.x, wid = tid >> 6, lane = tid & 63, r = lane & 15, qg = lane >> 4;
    bool isnew = (ch == NCH - 1);
    bool active = !isnew || (wid == 0);
    __shared__ __align__(16) char smem[128 * VT_PAD * 2];
    u16* Vt = (u16*)smem;
    float* Osh = (float*)smem;
    __shared__ __align__(16) u16 Plds[4][512];
    __shared__ float lsh[4][16];

    const float* vbase_wg = vc + ((size_t)bh * KVC + ch * 128) * DD;
    const u16* vrn = vr + (size_t)bh * SS * DD;

    if (!isnew) {
#pragma unroll
        for (int i = 0; i < 8; ++i) {
            int flat = i * 256 + tid;
            int c4 = flat & 31, rp = flat >> 5;
            const float* p0 = vbase_wg + (size_t)(2 * rp) * DD + c4 * 4;
            float4 a = *(const float4*)p0;
            float4 b = *(const float4*)(p0 + DD);
#pragma unroll
            for (int c = 0; c < 4; ++c) {
                unsigned lo = (unsigned)(u16)f2bfs((&a.x)[c]);
                unsigned hi = (unsigned)(u16)f2bfs((&b.x)[c]);
                *(unsigned*)(Vt + (size_t)(c4 * 4 + c) * VT_PAD + 2 * rp) = lo | (hi << 16);
            }
        }
    } else {
#pragma unroll
        for (int i = 0; i < 16; ++i) {
            int flat = i * 256 + tid;
            int key = flat >> 7, d = flat & 127;
            u16 v = (key < SS) ? vrn[(size_t)key * DD + d] : (u16)0;
            Vt[(size_t)d * VT_PAD + key] = v;
        }
    }
    __syncthreads();

    float lrow[4] = {0.f, 0.f, 0.f, 0.f};
    f32x4 oacc[8];
#pragma unroll
    for (int nt = 0; nt < 8; ++nt) oacc[nt] = (f32x4){0.f, 0.f, 0.f, 0.f};

    if (active) {
        s16x8 aq[4];
#pragma unroll
        for (int kk = 0; kk < 4; ++kk)
            aq[kk] = *(const s16x8*)(qr + (size_t)(bh * 16 + r) * DD + kk * 32 + qg * 8);
        const float* kbase = kc + ((size_t)bh * KVC + ch * 128 + wid * 32) * DD;
        const u16* krn = kr + (size_t)bh * SS * DD;

        f32x4 st[2];
        st[0] = (f32x4){0.f,0.f,0.f,0.f};
        st[1] = (f32x4){0.f,0.f,0.f,0.f};
#pragma unroll
        for (int t = 0; t < 2; ++t) {
            if (isnew && t == 1) continue;
#pragma unroll
            for (int kk = 0; kk < 4; ++kk) {
                s16x8 bk;
                if (isnew) {
                    bk = *(const s16x8*)(krn + (size_t)(t * 16 + r) * DD + kk * 32 + qg * 8);
                } else {
                    const float* p = kbase + (size_t)(t * 16 + r) * DD + kk * 32 + qg * 8;
                    float4 xx = *(const float4*)p;
                    float4 yy = *(const float4*)(p + 4);
                    bk[0]=f2bfs(xx.x); bk[1]=f2bfs(xx.y); bk[2]=f2bfs(xx.z); bk[3]=f2bfs(xx.w);
                    bk[4]=f2bfs(yy.x); bk[5]=f2bfs(yy.y); bk[6]=f2bfs(yy.z); bk[7]=f2bfs(yy.w);
                }
                st[t] = __builtin_amdgcn_mfma_f32_16x16x32_bf16(aq[kk], bk, st[t], 0, 0, 0);
            }
        }
#pragma unroll
        for (int t = 0; t < 2; ++t)
#pragma unroll
            for (int v = 0; v < 4; ++v) {
                float s = st[t][v] * ATT_SCALE;
                if (isnew && (t == 1 || r > qg * 4 + v)) s = -1e9f;
                st[t][v] = __expf(s);
            }
#pragma unroll
        for (int v = 0; v < 4; ++v) {
            float ss = st[0][v] + st[1][v];
            for (int msk = 1; msk < 16; msk <<= 1) ss += __shfl_xor(ss, msk);
            lrow[v] = ss;
        }
#pragma unroll
        for (int t = 0; t < 2; ++t)
#pragma unroll
            for (int v = 0; v < 4; ++v)
                Plds[wid][(qg * 4 + v) * 32 + t * 16 + r] = (u16)f2bfs(st[t][v]);
        s16x8 ap = *(const s16x8*)(&Plds[wid][r * 32 + qg * 8]);
#pragma unroll
        for (int nt = 0; nt < 8; ++nt) {
            s16x8 bv = *(const s16x8*)(Vt + (size_t)(nt * 16 + r) * VT_PAD + wid * 32 + qg * 8);
            oacc[nt] = __builtin_amdgcn_mfma_f32_16x16x32_bf16(ap, bv, oacc[nt], 0, 0, 0);
        }
    }
    __syncthreads();   // all Vt reads done; region becomes Osh
#pragma unroll
    for (int nt = 0; nt < 8; ++nt)
#pragma unroll
        for (int v = 0; v < 4; ++v)
            Osh[(size_t)(wid * 16 + qg * 4 + v) * OSH_PAD + nt * 16 + r] = oacc[nt][v];
    if (r == 0) {
#pragma unroll
        for (int v = 0; v < 4; ++v) lsh[wid][qg * 4 + v] = lrow[v];
    }
    __syncthreads();
    int q = tid >> 4, dg = tid & 15;
    float L = lsh[0][q] + lsh[1][q] + lsh[2][q] + lsh[3][q];
    float o[8];
#pragma unroll
    for (int j = 0; j < 8; ++j) o[j] = 0.f;
#pragma unroll
    for (int w = 0; w < 4; ++w) {
        const float* op = Osh + (size_t)(w * 16 + q) * OSH_PAD + dg * 8;
        float4 a = *(const float4*)op;
        float4 b = *(const float4*)(op + 4);
        o[0]+=a.x; o[1]+=a.y; o[2]+=a.z; o[3]+=a.w;
        o[4]+=b.x; o[5]+=b.y; o[6]+=b.z; o[7]+=b.w;
    }
    float* po = part_o + ((size_t)bh * NCH + ch) * (SS * DD) + q * DD + dg * 8;
    float4 o0; o0.x=o[0]; o0.y=o[1]; o0.z=o[2]; o0.w=o[3];
    float4 o1; o1.x=o[4]; o1.y=o[5]; o1.z=o[6]; o1.w=o[7];
    *(float4*)po = o0;
    *(float4*)(po + 4) = o1;
    if (dg == 0) part_l[((size_t)bh * NCH + ch) * 16 + q] = L;
}

// ---------- combine partials (pure sum / L) -> oa bf16 --------------------------------
__global__ __launch_bounds__(256) void attn_comb_k(const float* __restrict__ part_o,
                                                   const float* __restrict__ part_l,
                                                   u16* __restrict__ oa) {
    int bh = blockIdx.x, tid = threadIdx.x;
    int q = tid >> 4, dg = tid & 15;
    float L = 0.f;
#pragma unroll
    for (int c = 0; c < NCH; ++c) L += part_l[((size_t)bh * NCH + c) * 16 + q];
    float o[8];
#pragma unroll
    for (int j = 0; j < 8; ++j) o[j] = 0.f;
#pragma unroll
    for (int c = 0; c < NCH; ++c) {
        const float* po = part_o + ((size_t)bh * NCH + c) * (SS * DD) + q * DD + dg * 8;
        float4 a = *(const float4*)po;
        float4 b = *(const float4*)(po + 4);
        o[0]+=a.x; o[1]+=a.y; o[2]+=a.z; o[3]+=a.w;
        o[4]+=b.x; o[5]+=b.y; o[6]+=b.z; o[7]+=b.w;
    }
    float inv = 1.f / L;
    int b = bh / HH, h = bh % HH;
    u16* yp = oa + (size_t)(b * SS + q) * HIDN + h * DD + dg * 8;
    s16x8 ov;
#pragma unroll
    for (int j = 0; j < 8; ++j) ov[j] = f2bfs(o[j] * inv);
    *(s16x8*)yp = ov;
}

// ---------- Wo GEMM + residual, A staged in LDS; WG = 4 waves, grid (12,16) -----------
__global__ __launch_bounds__(256) void wo_res_k(const u16* __restrict__ oa,
                                                const u16* __restrict__ WoT,
                                                float* __restrict__ h) {
    int tid = threadIdx.x, wid = tid >> 6, lane = tid & 63, r = lane & 15, qg = lane >> 4;
    int b = blockIdx.y;
    __shared__ u16 A[16][AP];
#pragma unroll
    for (int i = 0; i < 6; ++i) {
        int idx8 = i * 256 + tid;
        int row = idx8 / 96, c8 = idx8 % 96;
        *(s16x8*)(&A[row][c8 * 8]) =
            *(const s16x8*)(oa + (size_t)(b * 16 + row) * HIDN + c8 * 8);
    }
    __syncthreads();
    int n0 = blockIdx.x * 64 + wid * 16;
    f32x4 acc = (f32x4){0.f, 0.f, 0.f, 0.f};
#pragma unroll 4
    for (int k0 = 0; k0 < HIDN; k0 += 32) {
        s16x8 a  = *(const s16x8*)(&A[r][k0 + qg * 8]);
        s16x8 bw = *(const s16x8*)(WoT + (size_t)(n0 + r) * HIDN + k0 + qg * 8);
        acc = __builtin_amdgcn_mfma_f32_16x16x32_bf16(a, bw, acc, 0, 0, 0);
    }
#pragma unroll
    for (int v = 0; v < 4; ++v)
        h[(size_t)(b * 16 + qg * 4 + v) * HIDN + n0 + r] += acc[v];
}

// ---------- fused rmsnorm2 + gate/up GEMM + SwiGLU; WG = 4 waves, grid (32,16) --------
__global__ __launch_bounds__(256) void ln2gu_k(const float* __restrict__ h,
                                               const float* __restrict__ ln2w,
                                               const u16* __restrict__ WgT,
                                               const u16* __restrict__ WuT,
                                               u16* __restrict__ F) {
    int tid = threadIdx.x, wid = tid >> 6, lane = tid & 63, r = lane & 15, qg = lane >> 4;
    int m0 = blockIdx.y * 16;
    __shared__ u16 A[16][AP];
    float wln[12];
#pragma unroll
    for (int i = 0; i < 12; ++i) wln[i] = ln2w[lane * 12 + i];
#pragma unroll
    for (int i = 0; i < 4; ++i) {
        int row = wid * 4 + i;
        const float* xp = h + (size_t)(m0 + row) * HIDN + lane * 12;
        float4 a = *(const float4*)xp;
        float4 bb = *(const float4*)(xp + 4);
        float4 c = *(const float4*)(xp + 8);
        float s = a.x*a.x + a.y*a.y + a.z*a.z + a.w*a.w
                + bb.x*bb.x + bb.y*bb.y + bb.z*bb.z + bb.w*bb.w
                + c.x*c.x + c.y*c.y + c.z*c.z + c.w*c.w;
        for (int m = 1; m < 64; m <<= 1) s += __shfl_xor(s, m);
        float rq = rsqrtf(s * (1.f / 768.f) + 1e-6f);
#pragma unroll
        for (int j = 0; j < 3; ++j) {
            float4 xv = (j == 0) ? a : (j == 1) ? bb : c;
            u16x4 o;
#pragma unroll
            for (int t = 0; t < 4; ++t) o[t] = (u16)f2bfs((&xv.x)[t] * rq * wln[j * 4 + t]);
            *(u16x4*)(&A[row][lane * 12 + j * 4]) = o;
        }
    }
    __syncthreads();
    int n0 = blockIdx.x * 64 + wid * 16;
    f32x4 ag = (f32x4){0.f, 0.f, 0.f, 0.f};
    f32x4 au = (f32x4){0.f, 0.f, 0.f, 0.f};
#pragma unroll 4
    for (int k0 = 0; k0 < HIDN; k0 += 32) {
        s16x8 a  = *(const s16x8*)(&A[r][k0 + qg * 8]);
        s16x8 bg = *(const s16x8*)(WgT + (size_t)(n0 + r) * HIDN + k0 + qg * 8);
        ag = __builtin_amdgcn_mfma_f32_16x16x32_bf16(a, bg, ag, 0, 0, 0);
        s16x8 bu = *(const s16x8*)(WuT + (size_t)(n0 + r) * HIDN + k0 + qg * 8);
        au = __builtin_amdgcn_mfma_f32_16x16x32_bf16(a, bu, au, 0, 0, 0);
    }
#pragma unroll
    for (int v = 0; v < 4; ++v) {
        float gv = ag[v], uv = au[v];
        float f = gv / (1.f + __expf(-gv)) * uv;
        F[(size_t)(m0 + qg * 4 + v) * FFN + n0 + r] = (u16)f2bfs(f);
    }
}

// ---------- down GEMM + residual (split-K=4, atomics), A staged; grid (12,16,4) -------
__global__ __launch_bounds__(256) void down_res_k(const u16* __restrict__ F,
                                                  const u16* __restrict__ WdT,
                                                  float* __restrict__ H) {
    int tid = threadIdx.x, wid = tid >> 6, lane = tid & 63, r = lane & 15, qg = lane >> 4;
    int m0 = blockIdx.y * 16;
    int kbeg = blockIdx.z * 512;
    __shared__ u16 A[16][AP2];
#pragma unroll
    for (int i = 0; i < 4; ++i) {
        int idx8 = i * 256 + tid;
        int row = idx8 >> 6, c8 = idx8 & 63;
        *(s16x8*)(&A[row][c8 * 8]) =
            *(const s16x8*)(F + (size_t)(m0 + row) * FFN + kbeg + c8 * 8);
    }
    __syncthreads();
    int n0 = blockIdx.x * 64 + wid * 16;
    f32x4 acc = (f32x4){0.f, 0.f, 0.f, 0.f};
#pragma unroll 4
    for (int k0 = 0; k0 < 512; k0 += 32) {
        s16x8 a  = *(const s16x8*)(&A[r][k0 + qg * 8]);
        s16x8 bw = *(const s16x8*)(WdT + (size_t)(n0 + r) * FFN + kbeg + k0 + qg * 8);
        acc = __builtin_amdgcn_mfma_f32_16x16x32_bf16(a, bw, acc, 0, 0, 0);
    }
#pragma unroll
    for (int v = 0; v < 4; ++v)
        atomicAdd(&H[(size_t)(m0 + qg * 4 + v) * HIDN + n0 + r], acc[v]);
}

extern "C" void kernel_launch(void* const* d_in, const int* in_sizes, int n_in,
                              void* d_out, int out_size, void* d_ws, size_t ws_size,
                              hipStream_t stream) {
    (void)in_sizes; (void)n_in; (void)out_size; (void)ws_size;
    const float* emb     = (const float*)d_in[0];
    const float* k_cache = (const float*)d_in[4];
    const float* v_cache = (const float*)d_in[5];
    const float* Wq = (const float*)d_in[6];
    const float* bq = (const float*)d_in[7];
    const float* Wk = (const float*)d_in[8];
    const float* bk = (const float*)d_in[9];
    const float* Wv = (const float*)d_in[10];
    const float* bv = (const float*)d_in[11];
    const float* Wo = (const float*)d_in[12];
    const float* Wg = (const float*)d_in[13];
    const float* Wu = (const float*)d_in[14];
    const float* Wd = (const float*)d_in[15];
    const float* ln1 = (const float*)d_in[16];
    const float* ln2 = (const float*)d_in[17];
    const float* normf = (const float*)d_in[18];
    float* out = (float*)d_out;

    char* p = (char*)d_ws;
    auto alloc = [&](size_t bytes) { void* r = p; p += (bytes + 255) & ~255ull; return r; };
    const size_t WQKV = (size_t)HIDN * HH * DD;
    const size_t WMLP = (size_t)HIDN * FFN;
    u16* WqT = (u16*)alloc(LNUM * WQKV * 2);
    u16* WkT = (u16*)alloc(LNUM * WQKV * 2);
    u16* WvT = (u16*)alloc(LNUM * WQKV * 2);
    u16* WoT = (u16*)alloc(LNUM * WQKV * 2);
    u16* WgT = (u16*)alloc(LNUM * WMLP * 2);
    u16* WuT = (u16*)alloc(LNUM * WMLP * 2);
    u16* WdT = (u16*)alloc(LNUM * WMLP * 2);
    const int TOK = BB * SS;
    const size_t EMB_N = (size_t)TOK * HIDN;
    float* h  = (float*)alloc(EMB_N * 4);
    u16* qr   = (u16*)alloc((size_t)BB * HH * SS * DD * 2);
    u16* kr   = (u16*)alloc((size_t)BB * HH * SS * DD * 2);
    u16* vr   = (u16*)alloc((size_t)BB * HH * SS * DD * 2);
    u16* oa   = (u16*)alloc(EMB_N * 2);
    u16* fb   = (u16*)alloc((size_t)TOK * FFN * 2);
    float* po  = (float*)alloc((size_t)96 * NCH * SS * DD * 4);
    float* pl  = (float*)alloc((size_t)96 * NCH * 16 * 4);
    float2* tab = (float2*)alloc(16 * 64 * sizeof(float2));

    wtrans_all_k<<<dim3(1728, LNUM), 256, 0, stream>>>(Wq, Wk, Wv, Wo, Wg, Wu, Wd,
                                                       WqT, WkT, WvT, WoT, WgT, WuT, WdT,
                                                       emb, h, tab);

    const size_t KVOFF = (size_t)BB * HH * KVC * DD;
    for (int l = 0; l < LNUM; ++l) {
        qkv_k<<<dim3(3 * HH, BB), 256, 0, stream>>>(h, ln1 + l * HIDN,
            WqT + l * WQKV, WkT + l * WQKV, WvT + l * WQKV,
            bq + l * HH * DD, bk + l * HH * DD, bv + l * HH * DD, tab, qr, kr, vr);
        attn_part2_k<<<dim3(BB * HH, NCH), 256, 0, stream>>>(qr, kr, vr,
            k_cache + (size_t)l * KVOFF, v_cache + (size_t)l * KVOFF, po, pl);
        attn_comb_k<<<BB * HH, 256, 0, stream>>>(po, pl, oa);
        wo_res_k<<<dim3(12, BB), 256, 0, stream>>>(oa, WoT + l * WQKV, h);
        ln2gu_k<<<dim3(32, BB), 256, 0, stream>>>(h, ln2 + l * HIDN,
            WgT + l * WMLP, WuT + l * WMLP, fb);
        down_res_k<<<dim3(12, BB, 4), 256, 0, stream>>>(fb, WdT + l * WMLP, h);
    }
    rmsnorm_f_k<<<TOK, 64, 0, stream>>>(h, normf, out);
}